// Round 10
// baseline (258.147 us; speedup 1.0000x reference)
//
#include <hip/hip_runtime.h>
#include <hip/hip_bf16.h>
#include <math.h>

#define B_ 2
#define TX_ 1024
#define TY_ 4096
#define C_ 768
#define H_ 12
#define D_ 64
#define NSPLIT 4
#define R_ (B_ * H_ * TX_)

typedef __bf16 bf16x8 __attribute__((ext_vector_type(8)));
typedef float floatx4 __attribute__((ext_vector_type(4)));

__device__ __forceinline__ void async_copy16(const void* g, void* l) {
    __builtin_amdgcn_global_load_lds(
        (const __attribute__((address_space(1))) unsigned int*)g,
        (__attribute__((address_space(3))) unsigned int*)l,
        16, 0, 0);
}

__device__ __forceinline__ bf16x8 cvt8(const float* s) {
    bf16x8 r;
#pragma unroll
    for (int i = 0; i < 8; i++) r[i] = (__bf16)s[i];
    return r;
}

// ---------------------------------------------------------------------------
// prep: ONE launch: (a) 3 weight transposes W(768xN f32)->Wt(Nx768 bf16),
// (b) x,y f32->bf16 conversion (8 elems/thread).
// ---------------------------------------------------------------------------
__global__ __launch_bounds__(256)
void prep(const float* __restrict__ x,  __bf16* __restrict__ xb,
          const float* __restrict__ y,  __bf16* __restrict__ yb,
          const float* __restrict__ Wq, __bf16* __restrict__ Wqt,
          const float* __restrict__ Wkv,__bf16* __restrict__ Wkvt,
          const float* __restrict__ Wpr,__bf16* __restrict__ Wprt)
{
    __shared__ float tile[32][33];
    const int bid = blockIdx.x;
    if (bid >= 2304) {
        const int cb = bid - 2304;
        const float* src; __bf16* dst; size_t base;
        if (cb < 768) { src = x; dst = xb; base = (size_t)cb * 2048; }
        else          { src = y; dst = yb; base = (size_t)(cb - 768) * 2048; }
        const size_t i = base + threadIdx.x * 8;
        float4 v0 = *(const float4*)(src + i);
        float4 v1 = *(const float4*)(src + i + 4);
        bf16x8 p;
        p[0] = (__bf16)v0.x; p[1] = (__bf16)v0.y; p[2] = (__bf16)v0.z; p[3] = (__bf16)v0.w;
        p[4] = (__bf16)v1.x; p[5] = (__bf16)v1.y; p[6] = (__bf16)v1.z; p[7] = (__bf16)v1.w;
        *(bf16x8*)(dst + i) = p;
        return;
    }
    const int bxr = bid % 96;
    const int byr = bid / 96;
    const float* W; __bf16* Wt; int N, nb; float scale = 1.0f;
    if (bxr < 24)      { W = Wq;  Wt = Wqt;  N = C_;     nb = bxr;      scale = 0.125f; }
    else if (bxr < 72) { W = Wkv; Wt = Wkvt; N = 2 * C_; nb = bxr - 24; }
    else               { W = Wpr; Wt = Wprt; N = C_;     nb = bxr - 72; }
    const int bx = nb * 32;
    const int by = byr * 32;
    const int tx = threadIdx.x & 31, ty = threadIdx.x >> 5;
#pragma unroll
    for (int i = 0; i < 4; i++)
        tile[ty + i * 8][tx] = W[(size_t)(by + ty + i * 8) * N + bx + tx];
    __syncthreads();
#pragma unroll
    for (int i = 0; i < 4; i++)
        Wt[(size_t)(bx + ty + i * 8) * C_ + by + tx] =
            (__bf16)(tile[tx][ty + i * 8] * scale);
}

// ---------------------------------------------------------------------------
// Fused Q + KV MFMA GEMM, 1D grid 864 blocks (96 Q tiles first, then 768 KV).
// 128x128 tile, two 32-k chunks per barrier pair (BK=64 effective).
// ---------------------------------------------------------------------------
__global__ __launch_bounds__(256)
void gemm_qkv(const __bf16* __restrict__ xb, const __bf16* __restrict__ Wqt,
              const __bf16* __restrict__ yb, const __bf16* __restrict__ Wkvt,
              __bf16* __restrict__ Qbh, __bf16* __restrict__ Kbh,
              __bf16* __restrict__ Vtb,
              const float* __restrict__ x_t, const float* __restrict__ y_t,
              const float* __restrict__ inv_freq)
{
    const int bid = blockIdx.x;
    const bool isQ = (bid < 96);
    const __bf16* A; const __bf16* Bt; const float* t_arr;
    int row0, n0, T, TSH;
    if (isQ) {
        A = xb; Bt = Wqt; t_arr = x_t;
        row0 = (bid / 6) * 128; n0 = (bid % 6) * 128; T = TX_; TSH = 10;
    } else {
        const int r = bid - 96;
        A = yb; Bt = Wkvt; t_arr = y_t;
        row0 = (r / 12) * 128; n0 = (r % 12) * 128; T = TY_; TSH = 12;
    }
    const bool isV = (!isQ) && (n0 >= C_);

    __shared__ __align__(16) float smem_f[8192];   // 32768 B
    __bf16* smem_b = (__bf16*)smem_f;

    const int tid  = threadIdx.x;
    const int wave = tid >> 6;
    const int lane = tid & 63;
    const int m16  = lane & 15;
    const int quad = lane >> 4;
    const int wm   = wave >> 1;
    const int wn   = wave & 1;

    floatx4 acc[4][4];
#pragma unroll
    for (int i = 0; i < 4; i++)
#pragma unroll
        for (int j = 0; j < 4; j++) acc[i][j] = (floatx4){0.f, 0.f, 0.f, 0.f};

    int srow[4], scol[4];
#pragma unroll
    for (int j = 0; j < 4; j++) {
        int e = j * 2048 + wave * 512 + lane * 8;
        int e2 = e & 4095;
        srow[j] = e2 >> 5;
        scol[j] = e2 & 31;
    }

    for (int k0 = 0; k0 < C_; k0 += 64) {
        __syncthreads();
#pragma unroll
        for (int c = 0; c < 2; c++) {
            const int kk = k0 + c * 32;
#pragma unroll
            for (int j = 0; j < 4; j++) {
                const __bf16* src = (j < 2)
                    ? A  + (size_t)(row0 + srow[j]) * C_ + (kk + scol[j])
                    : Bt + (size_t)(n0   + srow[j]) * C_ + (kk + scol[j]);
                async_copy16(src, (char*)smem_f + c * 16384 + j * 4096 + wave * 1024);
            }
        }
        __syncthreads();

#pragma unroll
        for (int c = 0; c < 2; c++) {
            const __bf16* As = smem_b + c * 8192;
            const __bf16* Bs = As + 4096;
            bf16x8 af[4], bfr[4];
#pragma unroll
            for (int i = 0; i < 4; i++)
                af[i] = *(const bf16x8*)(As + (size_t)(wm * 64 + i * 16 + m16) * 32 + quad * 8);
#pragma unroll
            for (int j = 0; j < 4; j++)
                bfr[j] = *(const bf16x8*)(Bs + (size_t)(wn * 64 + j * 16 + m16) * 32 + quad * 8);
#pragma unroll
            for (int i = 0; i < 4; i++)
#pragma unroll
                for (int j = 0; j < 4; j++)
                    acc[i][j] = __builtin_amdgcn_mfma_f32_16x16x32_bf16(af[i], bfr[j], acc[i][j], 0, 0, 0);
        }
    }

    // ---- epilogue (LDS-staged, full-line stores) ----
    const int STR = 132;
    float* fs = smem_f;

#pragma unroll
    for (int i = 0; i < 4; i++) {
        __syncthreads();
#pragma unroll
        for (int j = 0; j < 4; j++) {
            const int col_l = wn * 64 + j * 16 + m16;
#pragma unroll
            for (int r = 0; r < 4; r++) {
                const int row_l = quad * 4 + r;
                float v = acc[i][j][r];
                if (!isV) {
                    const float vp = __shfl_xor(v, 1);
                    const int row = row0 + wm * 64 + i * 16 + row_l;
                    const int cc = (n0 + col_l) & (D_ - 1);
                    const float fr = t_arr[row] * inv_freq[cc >> 1];
                    const float sn = __sinf(fr), cs = __cosf(fr);
                    v = (m16 & 1) ? (v * cs + vp * sn) : (v * cs - vp * sn);
                }
                fs[(wm * 16 + row_l) * STR + col_l] = v;
            }
        }
        __syncthreads();

        if (!isV) {
            __bf16* outb = isQ ? Qbh : Kbh;
            const int r32 = tid >> 3;
            const int lane8 = tid & 7;
            const int grow = row0 + (r32 >> 4) * 64 + i * 16 + (r32 & 15);
            const int bb = grow >> TSH;
            const int rk = grow & (T - 1);
            const int h  = (n0 >> 6) + (lane8 >> 2);
            const int d0 = (lane8 & 3) * 16;
            __bf16* gp = outb + ((size_t)(bb * H_ + h) * T + rk) * 64 + d0;
            const float* sp = &fs[r32 * STR + lane8 * 16];
            *(bf16x8*)gp       = cvt8(sp);
            *(bf16x8*)(gp + 8) = cvt8(sp + 8);
        } else {
            const int dcol = tid >> 1;
            const int g16  = tid & 1;
            const int h  = ((n0 - C_) >> 6) + (dcol >> 6);
            const int dd = dcol & 63;
            const int kbase = row0 + g16 * 64 + i * 16;
            const int bb  = kbase >> 12;
            const int kin = kbase & (TY_ - 1);
            float tmp[16];
#pragma unroll
            for (int jj = 0; jj < 16; jj++)
                tmp[jj] = fs[(g16 * 16 + jj) * STR + dcol];
            __bf16* gp = Vtb + ((size_t)(bb * H_ + h) * 64 + dd) * TY_ + kin;
            *(bf16x8*)gp       = cvt8(tmp);
            *(bf16x8*)(gp + 8) = cvt8(tmp + 8);
        }
    }
}

// ---------------------------------------------------------------------------
// WAVE-AUTONOMOUS MFMA flash attention — zero block barriers.
// Each wave owns 16 q rows; K and V B-fragments are loaded DIRECTLY from
// global (Kb row-major, Vt d-major) — no LDS staging, no __syncthreads.
// Only LDS use: per-wave P C->A layout round-trip (wave-ordered DS ops).
// No-max softmax (scores O(1), shift-invariant). NSPLIT k-splits.
// ---------------------------------------------------------------------------
__global__ __launch_bounds__(256)
void attn_mfma(const __bf16* __restrict__ Qb,
               const __bf16* __restrict__ Kb,
               const __bf16* __restrict__ Vt,
               const float* __restrict__ x_t,
               const float* __restrict__ y_t,
               const int* __restrict__ dist_p,
               const int* __restrict__ min_dist_p,
               float* __restrict__ pacc,
               float* __restrict__ pml)
{
    __shared__ __align__(16) __bf16 Pt[4][16 * 64];   // 8 KB total

    const int tid  = threadIdx.x;
    const int wave = tid >> 6;
    const int m16  = tid & 15;
    const int quad = (tid & 63) >> 4;
    const int qt = blockIdx.x, bh = blockIdx.y, split = blockIdx.z;
    const int b = bh / H_;
    const int qbase = qt * 64 + wave * 16;

    const float dist = (float)dist_p[0];
    const float md   = (float)min_dist_p[0];
    const float* yt = y_t + (size_t)b * TY_;
    const float* xt = x_t + (size_t)b * TX_;

    // wave-local k-window (16 sorted q rows)
    const float xtlo = xt[qbase] - md;
    const float xthi = xt[qbase + 15] - md;
    int lo = 0, hi = TY_;
    while (lo < hi) { int mid = (lo + hi) >> 1; if (yt[mid] + dist < xtlo) lo = mid + 1; else hi = mid; }
    const int klo = lo;
    lo = 0; hi = TY_;
    while (lo < hi) { int mid = (lo + hi) >> 1; if (yt[mid] <= xthi) lo = mid + 1; else hi = mid; }
    const int khi = lo - 1;
    const int len = khi - klo + 1;

    int k0 = klo, k1 = klo;
    if (len > 0) {
        const int cnt = (len + NSPLIT - 1) / NSPLIT;
        k0 = klo + split * cnt;
        k1 = min(k0 + cnt, klo + len);
    }

    float xtq[4];
#pragma unroll
    for (int r = 0; r < 4; r++)
        xtq[r] = xt[qbase + quad * 4 + r] - md;

    const __bf16* qp = Qb + ((size_t)bh * TX_ + qbase + m16) * 64;
    const bf16x8 aq0 = *(const bf16x8*)(qp + quad * 8);
    const bf16x8 aq1 = *(const bf16x8*)(qp + 32 + quad * 8);

    const __bf16* kbase_p = Kb + (size_t)bh * TY_ * 64;
    const __bf16* vbase_p = Vt + (size_t)bh * 64 * TY_;

    float l[4];
    floatx4 o[4];
#pragma unroll
    for (int r = 0; r < 4; r++) l[r] = 0.f;
#pragma unroll
    for (int t = 0; t < 4; t++) o[t] = (floatx4){0.f, 0.f, 0.f, 0.f};

    __bf16* pt = Pt[wave];

    for (int kc = k0; kc < k1; kc += 64) {
        // QK^T: S[16q x 64k]; K B-frags direct from global
        floatx4 s[4];
        float ytv[4];
#pragma unroll
        for (int c = 0; c < 4; c++) {
            const int kg = min(kc + c * 16 + m16, TY_ - 1);
            ytv[c] = yt[kg];
            const __bf16* kp = kbase_p + (size_t)kg * 64;
            const bf16x8 bk0 = *(const bf16x8*)(kp + quad * 8);
            const bf16x8 bk1 = *(const bf16x8*)(kp + 32 + quad * 8);
            s[c] = (floatx4){0.f, 0.f, 0.f, 0.f};
            s[c] = __builtin_amdgcn_mfma_f32_16x16x32_bf16(aq0, bk0, s[c], 0, 0, 0);
            s[c] = __builtin_amdgcn_mfma_f32_16x16x32_bf16(aq1, bk1, s[c], 0, 0, 0);
        }

        // mask + exp + P write (C-layout), wave-local
#pragma unroll
        for (int r = 0; r < 4; r++) {
#pragma unroll
            for (int c = 0; c < 4; c++) {
                const int kg = kc + c * 16 + m16;
                const bool v = (kg < k1) && (xtq[r] >= ytv[c]) && (xtq[r] <= ytv[c] + dist);
                const __bf16 pb = v ? (__bf16)__expf(s[c][r]) : (__bf16)0.f;
                l[r] += (float)pb;
                pt[(quad * 4 + r) * 64 + c * 16 + m16] = pb;
            }
        }
        // P read (A-layout) — same wave, DS ops ordered, no barrier needed
        const bf16x8 ap0 = *(const bf16x8*)(pt + m16 * 64 + quad * 8);
        const bf16x8 ap1 = *(const bf16x8*)(pt + m16 * 64 + 32 + quad * 8);

        // PV: V B-frags direct from global (Vt d-major; +128 elem pad covers
        // the masked straddle past TY)
#pragma unroll
        for (int t = 0; t < 4; t++) {
            const __bf16* vp = vbase_p + (size_t)(t * 16 + m16) * TY_;
            const bf16x8 bv0 = *(const bf16x8*)(vp + kc + quad * 8);
            const bf16x8 bv1 = *(const bf16x8*)(vp + kc + 32 + quad * 8);
            o[t] = __builtin_amdgcn_mfma_f32_16x16x32_bf16(ap0, bv0, o[t], 0, 0, 0);
            o[t] = __builtin_amdgcn_mfma_f32_16x16x32_bf16(ap1, bv1, o[t], 0, 0, 0);
        }
    }

#pragma unroll
    for (int r = 0; r < 4; r++) {
#pragma unroll
        for (int w = 1; w < 16; w <<= 1)
            l[r] += __shfl_xor(l[r], w);
    }

#pragma unroll
    for (int t = 0; t < 4; t++)
#pragma unroll
        for (int r = 0; r < 4; r++) {
            const size_t gr = (size_t)bh * TX_ + qbase + quad * 4 + r;
            pacc[((size_t)split * R_ + gr) * 64 + t * 16 + m16] = o[t][r];
        }
    if (m16 == 0) {
#pragma unroll
        for (int r = 0; r < 4; r++) {
            const size_t gr = (size_t)bh * TX_ + qbase + quad * 4 + r;
            pml[(size_t)split * R_ + gr] = l[r];
        }
    }
}

// ---------------------------------------------------------------------------
// Combine NSPLIT partials -> Ob bf16 (B,TX,C)
// ---------------------------------------------------------------------------
__global__ __launch_bounds__(256)
void combine_kernel(const float* __restrict__ pacc,
                    const float* __restrict__ pml,
                    __bf16* __restrict__ O)
{
    const int d   = threadIdx.x;
    const int sub = threadIdx.y;
    const size_t r = (size_t)blockIdx.x * 4 + sub;
    const int bh  = (int)(r / TX_);
    const int txg = (int)(r % TX_);
    const int b = bh / H_, h = bh % H_;

    float L = 0.f, val = 0.f;
#pragma unroll
    for (int s = 0; s < NSPLIT; s++) {
        L   += pml[(size_t)s * R_ + r];
        val += pacc[((size_t)s * R_ + r) * 64 + d];
    }
    const float o = (L > 0.f) ? val / L : 0.f;
    O[(size_t)(b * TX_ + txg) * C_ + h * D_ + d] = (__bf16)o;
}

// ---------------------------------------------------------------------------
// proj GEMM: out(M,768 f32) = A(M,768 bf16) @ Bt(768,768 bf16)^T
// ---------------------------------------------------------------------------
__global__ __launch_bounds__(256)
void gemm_proj(const __bf16* __restrict__ A,
               const __bf16* __restrict__ Bt,
               float* __restrict__ out0)
{
    __shared__ __align__(16) float smem_f[8192];
    __bf16* smem_b = (__bf16*)smem_f;

    const int tid  = threadIdx.x;
    const int wave = tid >> 6;
    const int lane = tid & 63;
    const int m16  = lane & 15;
    const int quad = lane >> 4;
    const int wm   = wave >> 1;
    const int wn   = wave & 1;
    const int row0 = blockIdx.y * 128;
    const int n0   = blockIdx.x * 128;

    floatx4 acc[4][4];
#pragma unroll
    for (int i = 0; i < 4; i++)
#pragma unroll
        for (int j = 0; j < 4; j++) acc[i][j] = (floatx4){0.f, 0.f, 0.f, 0.f};

    int srow[4], scol[4];
#pragma unroll
    for (int j = 0; j < 4; j++) {
        int e = j * 2048 + wave * 512 + lane * 8;
        int e2 = e & 4095;
        srow[j] = e2 >> 5;
        scol[j] = e2 & 31;
    }

    for (int k0 = 0; k0 < C_; k0 += 64) {
        __syncthreads();
#pragma unroll
        for (int c = 0; c < 2; c++) {
            const int kk = k0 + c * 32;
#pragma unroll
            for (int j = 0; j < 4; j++) {
                const __bf16* src = (j < 2)
                    ? A  + (size_t)(row0 + srow[j]) * C_ + (kk + scol[j])
                    : Bt + (size_t)(n0   + srow[j]) * C_ + (kk + scol[j]);
                async_copy16(src, (char*)smem_f + c * 16384 + j * 4096 + wave * 1024);
            }
        }
        __syncthreads();

#pragma unroll
        for (int c = 0; c < 2; c++) {
            const __bf16* As = smem_b + c * 8192;
            const __bf16* Bs = As + 4096;
            bf16x8 af[4], bfr[4];
#pragma unroll
            for (int i = 0; i < 4; i++)
                af[i] = *(const bf16x8*)(As + (size_t)(wm * 64 + i * 16 + m16) * 32 + quad * 8);
#pragma unroll
            for (int j = 0; j < 4; j++)
                bfr[j] = *(const bf16x8*)(Bs + (size_t)(wn * 64 + j * 16 + m16) * 32 + quad * 8);
#pragma unroll
            for (int i = 0; i < 4; i++)
#pragma unroll
                for (int j = 0; j < 4; j++)
                    acc[i][j] = __builtin_amdgcn_mfma_f32_16x16x32_bf16(af[i], bfr[j], acc[i][j], 0, 0, 0);
        }
    }

    const int STR = 132;
    float* fs = smem_f;
#pragma unroll
    for (int i = 0; i < 4; i++) {
        __syncthreads();
#pragma unroll
        for (int j = 0; j < 4; j++) {
            const int col_l = wn * 64 + j * 16 + m16;
#pragma unroll
            for (int r = 0; r < 4; r++)
                fs[(wm * 16 + quad * 4 + r) * STR + col_l] = acc[i][j][r];
        }
        __syncthreads();
        const int r32 = tid >> 3;
        const int lc  = (tid & 7) * 4;
        const int row = row0 + (r32 >> 4) * 64 + i * 16 + (r32 & 15);
        float* gp = out0 + (size_t)row * C_ + n0;
#pragma unroll
        for (int c2 = 0; c2 < 4; c2++) {
            float4 v4 = *(const float4*)&fs[r32 * STR + c2 * 32 + lc];
            *(float4*)(gp + c2 * 32 + lc) = v4;
        }
    }
}

// ---------------------------------------------------------------------------
extern "C" void kernel_launch(void* const* d_in, const int* in_sizes, int n_in,
                              void* d_out, int out_size, void* d_ws, size_t ws_size,
                              hipStream_t stream)
{
    const float* x        = (const float*)d_in[0];
    const float* x_t      = (const float*)d_in[1];
    const float* y        = (const float*)d_in[2];
    const float* y_t      = (const float*)d_in[3];
    const int*   dist     = (const int*)d_in[4];
    const int*   min_dist = (const int*)d_in[5];
    const float* Wq       = (const float*)d_in[6];
    const float* Wkv      = (const float*)d_in[7];
    const float* Wproj    = (const float*)d_in[8];
    const float* inv_freq = (const float*)d_in[9];
    float* out = (float*)d_out;

    const size_t QN = (size_t)B_ * TX_ * C_;
    const size_t KN = (size_t)B_ * TY_ * C_;

    float* ws = (float*)d_ws;
    float* pacc = ws; ws += (size_t)NSPLIT * R_ * 64;
    float* pml  = ws; ws += (size_t)NSPLIT * R_;
    __bf16* bws = (__bf16*)ws;
    __bf16* xb    = bws; bws += QN;
    __bf16* yb    = bws; bws += KN;
    __bf16* Wqt   = bws; bws += (size_t)C_ * C_;
    __bf16* Wkvt  = bws; bws += (size_t)C_ * 2 * C_;
    __bf16* Wprt  = bws; bws += (size_t)C_ * C_;
    __bf16* Ob    = bws; bws += QN;
    __bf16* Qbh   = bws; bws += QN;          // [bh][TX][64]
    __bf16* Kbh   = bws; bws += KN;          // [bh][TY][64]
    __bf16* Vtb   = bws; bws += KN + 128;    // [bh][64][TY] (+pad for straddle)

    prep<<<dim3(2304 + 3840), dim3(256), 0, stream>>>(
        x, xb, y, yb, Wq, Wqt, Wkv, Wkvt, Wproj, Wprt);

    gemm_qkv<<<dim3(864), dim3(256), 0, stream>>>(
        xb, Wqt, yb, Wkvt, Qbh, Kbh, Vtb, x_t, y_t, inv_freq);

    attn_mfma<<<dim3(TX_ / 64, B_ * H_, NSPLIT), dim3(256), 0, stream>>>(
        Qbh, Kbh, Vtb, x_t, y_t, dist, min_dist, pacc, pml);

    combine_kernel<<<dim3((unsigned)(R_ / 4)), dim3(64, 4), 0, stream>>>(
        pacc, pml, Ob);

    gemm_proj<<<dim3(C_ / 128, (B_ * TX_) / 128), dim3(256), 0, stream>>>(
        Ob, Wprt, out);
}

// Round 11
// 201.109 us; speedup vs baseline: 1.2836x; 1.2836x over previous
//
#include <hip/hip_runtime.h>
#include <hip/hip_bf16.h>
#include <math.h>

#define B_ 2
#define TX_ 1024
#define TY_ 4096
#define C_ 768
#define H_ 12
#define D_ 64
#define NSPLIT 4
#define R_ (B_ * H_ * TX_)

typedef __bf16 bf16x8 __attribute__((ext_vector_type(8)));
typedef float floatx4 __attribute__((ext_vector_type(4)));

__device__ __forceinline__ void async_copy16(const void* g, void* l) {
    __builtin_amdgcn_global_load_lds(
        (const __attribute__((address_space(1))) unsigned int*)g,
        (__attribute__((address_space(3))) unsigned int*)l,
        16, 0, 0);
}

__device__ __forceinline__ bf16x8 cvt8(const float* s) {
    bf16x8 r;
#pragma unroll
    for (int i = 0; i < 8; i++) r[i] = (__bf16)s[i];
    return r;
}

// ---------------------------------------------------------------------------
// prep: ONE launch: (a) 3 weight transposes W(768xN f32)->Wt(Nx768 bf16),
// (b) x,y f32->bf16 conversion (8 elems/thread).
// ---------------------------------------------------------------------------
__global__ __launch_bounds__(256)
void prep(const float* __restrict__ x,  __bf16* __restrict__ xb,
          const float* __restrict__ y,  __bf16* __restrict__ yb,
          const float* __restrict__ Wq, __bf16* __restrict__ Wqt,
          const float* __restrict__ Wkv,__bf16* __restrict__ Wkvt,
          const float* __restrict__ Wpr,__bf16* __restrict__ Wprt)
{
    __shared__ float tile[32][33];
    const int bid = blockIdx.x;
    if (bid >= 2304) {
        const int cb = bid - 2304;
        const float* src; __bf16* dst; size_t base;
        if (cb < 768) { src = x; dst = xb; base = (size_t)cb * 2048; }
        else          { src = y; dst = yb; base = (size_t)(cb - 768) * 2048; }
        const size_t i = base + threadIdx.x * 8;
        float4 v0 = *(const float4*)(src + i);
        float4 v1 = *(const float4*)(src + i + 4);
        bf16x8 p;
        p[0] = (__bf16)v0.x; p[1] = (__bf16)v0.y; p[2] = (__bf16)v0.z; p[3] = (__bf16)v0.w;
        p[4] = (__bf16)v1.x; p[5] = (__bf16)v1.y; p[6] = (__bf16)v1.z; p[7] = (__bf16)v1.w;
        *(bf16x8*)(dst + i) = p;
        return;
    }
    const int bxr = bid % 96;
    const int byr = bid / 96;
    const float* W; __bf16* Wt; int N, nb; float scale = 1.0f;
    if (bxr < 24)      { W = Wq;  Wt = Wqt;  N = C_;     nb = bxr;      scale = 0.125f; }
    else if (bxr < 72) { W = Wkv; Wt = Wkvt; N = 2 * C_; nb = bxr - 24; }
    else               { W = Wpr; Wt = Wprt; N = C_;     nb = bxr - 72; }
    const int bx = nb * 32;
    const int by = byr * 32;
    const int tx = threadIdx.x & 31, ty = threadIdx.x >> 5;
#pragma unroll
    for (int i = 0; i < 4; i++)
        tile[ty + i * 8][tx] = W[(size_t)(by + ty + i * 8) * N + bx + tx];
    __syncthreads();
#pragma unroll
    for (int i = 0; i < 4; i++)
        Wt[(size_t)(bx + ty + i * 8) * C_ + by + tx] =
            (__bf16)(tile[tx][ty + i * 8] * scale);
}

// ---------------------------------------------------------------------------
// Fused Q + KV MFMA GEMM, 1D grid 1728 blocks (192 Q tiles first, 1536 KV).
// 64x128 tile (64 rows for load balance: 6.75 blocks/CU, 6 resident at
// LDS 24KB), two 32-k chunks per barrier pair (BK=64 effective).
// Wave layout: 2x2, each wave 32 rows x 64 cols -> acc[2][4].
//   bid <  192: Q : rope -> Qbh [bh][TX][64]
//   bid >= 192: KV: n0<C_ rope -> Kbh [bh][TY][64]; n0>=C_ -> Vtb [bh][64][TY]
// ---------------------------------------------------------------------------
__global__ __launch_bounds__(256)
void gemm_qkv(const __bf16* __restrict__ xb, const __bf16* __restrict__ Wqt,
              const __bf16* __restrict__ yb, const __bf16* __restrict__ Wkvt,
              __bf16* __restrict__ Qbh, __bf16* __restrict__ Kbh,
              __bf16* __restrict__ Vtb,
              const float* __restrict__ x_t, const float* __restrict__ y_t,
              const float* __restrict__ inv_freq)
{
    const int bid = blockIdx.x;
    const bool isQ = (bid < 192);
    const __bf16* A; const __bf16* Bt; const float* t_arr;
    int row0, n0, T, TSH;
    if (isQ) {
        A = xb; Bt = Wqt; t_arr = x_t;
        row0 = (bid / 6) * 64; n0 = (bid % 6) * 128; T = TX_; TSH = 10;
    } else {
        const int r = bid - 192;
        A = yb; Bt = Wkvt; t_arr = y_t;
        row0 = (r / 12) * 64; n0 = (r % 12) * 128; T = TY_; TSH = 12;
    }
    const bool isV = (!isQ) && (n0 >= C_);

    __shared__ __align__(16) float smem_f[6144];   // 24576 B: 2 x (4KB A + 8KB B)
    __bf16* smem_b = (__bf16*)smem_f;

    const int tid  = threadIdx.x;
    const int wave = tid >> 6;
    const int lane = tid & 63;
    const int m16  = lane & 15;
    const int quad = lane >> 4;
    const int wm   = wave >> 1;
    const int wn   = wave & 1;

    floatx4 acc[2][4];
#pragma unroll
    for (int i = 0; i < 2; i++)
#pragma unroll
        for (int j = 0; j < 4; j++) acc[i][j] = (floatx4){0.f, 0.f, 0.f, 0.f};

    // A staging: 64x32 bf16 = 4096 B = 256 lanes x 16 B (one issue)
    const int eA = wave * 512 + lane * 8;
    const int srA = eA >> 5, scA = eA & 31;
    // B staging: 128x32 bf16 = 8192 B = two issues j in {0,1}
    int srB[2], scB[2];
#pragma unroll
    for (int j = 0; j < 2; j++) {
        const int e = j * 2048 + wave * 512 + lane * 8;
        srB[j] = e >> 5; scB[j] = e & 31;
    }

    for (int k0 = 0; k0 < C_; k0 += 64) {
        __syncthreads();
#pragma unroll
        for (int c = 0; c < 2; c++) {
            const int kk = k0 + c * 32;
            async_copy16(A + (size_t)(row0 + srA) * C_ + (kk + scA),
                         (char*)smem_f + c * 12288 + wave * 1024);
#pragma unroll
            for (int j = 0; j < 2; j++)
                async_copy16(Bt + (size_t)(n0 + srB[j]) * C_ + (kk + scB[j]),
                             (char*)smem_f + c * 12288 + 4096 + j * 4096 + wave * 1024);
        }
        __syncthreads();

#pragma unroll
        for (int c = 0; c < 2; c++) {
            const __bf16* As = smem_b + c * 6144;
            const __bf16* Bs = As + 2048;
            bf16x8 af[2], bfr[4];
#pragma unroll
            for (int i = 0; i < 2; i++)
                af[i] = *(const bf16x8*)(As + (size_t)(wm * 32 + i * 16 + m16) * 32 + quad * 8);
#pragma unroll
            for (int j = 0; j < 4; j++)
                bfr[j] = *(const bf16x8*)(Bs + (size_t)(wn * 64 + j * 16 + m16) * 32 + quad * 8);
#pragma unroll
            for (int i = 0; i < 2; i++)
#pragma unroll
                for (int j = 0; j < 4; j++)
                    acc[i][j] = __builtin_amdgcn_mfma_f32_16x16x32_bf16(af[i], bfr[j], acc[i][j], 0, 0, 0);
        }
    }

    // ---- epilogue (LDS-staged, full-line stores), i in {0,1}: 32 rows each
    const int STR = 132;
    float* fs = smem_f;

#pragma unroll
    for (int i = 0; i < 2; i++) {
        __syncthreads();
#pragma unroll
        for (int j = 0; j < 4; j++) {
            const int col_l = wn * 64 + j * 16 + m16;
#pragma unroll
            for (int r = 0; r < 4; r++) {
                const int row_l = quad * 4 + r;
                float v = acc[i][j][r];
                if (!isV) {
                    const float vp = __shfl_xor(v, 1);
                    const int row = row0 + wm * 32 + i * 16 + row_l;
                    const int cc = (n0 + col_l) & (D_ - 1);
                    const float fr = t_arr[row] * inv_freq[cc >> 1];
                    const float sn = __sinf(fr), cs = __cosf(fr);
                    v = (m16 & 1) ? (v * cs + vp * sn) : (v * cs - vp * sn);
                }
                fs[(wm * 16 + row_l) * STR + col_l] = v;
            }
        }
        __syncthreads();

        if (!isV) {
            __bf16* outb = isQ ? Qbh : Kbh;
            const int r32 = tid >> 3;                 // 0..31
            const int lane8 = tid & 7;
            const int grow = row0 + (r32 >> 4) * 32 + i * 16 + (r32 & 15);
            const int bb = grow >> TSH;
            const int rk = grow & (T - 1);
            const int h  = (n0 >> 6) + (lane8 >> 2);
            const int d0 = (lane8 & 3) * 16;
            __bf16* gp = outb + ((size_t)(bb * H_ + h) * T + rk) * 64 + d0;
            const float* sp = &fs[r32 * STR + lane8 * 16];
            *(bf16x8*)gp       = cvt8(sp);
            *(bf16x8*)(gp + 8) = cvt8(sp + 8);
        } else {
            const int dcol = tid >> 1;                // 0..127
            const int g16  = tid & 1;                 // 16-row group
            const int h  = ((n0 - C_) >> 6) + (dcol >> 6);
            const int dd = dcol & 63;
            const int kbase = row0 + g16 * 32 + i * 16;
            const int bb  = kbase >> 12;
            const int kin = kbase & (TY_ - 1);
            float tmp[16];
#pragma unroll
            for (int jj = 0; jj < 16; jj++)
                tmp[jj] = fs[(g16 * 16 + jj) * STR + dcol];
            __bf16* gp = Vtb + ((size_t)(bb * H_ + h) * 64 + dd) * TY_ + kin;
            *(bf16x8*)gp       = cvt8(tmp);
            *(bf16x8*)(gp + 8) = cvt8(tmp + 8);
        }
    }
}

// ---------------------------------------------------------------------------
// MFMA flash attention (round-8 proven version): LDS-staged 32-k chunks,
// no-max softmax, block = 4 waves = 64 q rows, NSPLIT k-splits.
// ---------------------------------------------------------------------------
__global__ __launch_bounds__(256)
void attn_mfma(const __bf16* __restrict__ Qb,
               const __bf16* __restrict__ Kb,
               const __bf16* __restrict__ Vt,
               const float* __restrict__ x_t,
               const float* __restrict__ y_t,
               const int* __restrict__ dist_p,
               const int* __restrict__ min_dist_p,
               float* __restrict__ pacc,
               float* __restrict__ pml)
{
    __shared__ __align__(16) __bf16 Kc[32 * 64];
    __shared__ __align__(16) __bf16 Vc[64 * 32];
    __shared__ __align__(16) __bf16 Pt[4][16 * 32];

    const int tid  = threadIdx.x;
    const int wave = tid >> 6;
    const int m16  = tid & 15;
    const int quad = (tid & 63) >> 4;
    const int qt = blockIdx.x, bh = blockIdx.y, split = blockIdx.z;
    const int b = bh / H_;
    const int qblk  = qt * 64;
    const int qbase = qblk + wave * 16;

    const float dist = (float)dist_p[0];
    const float md   = (float)min_dist_p[0];
    const float* yt = y_t + (size_t)b * TY_;
    const float* xt = x_t + (size_t)b * TX_;

    const float xtmin = xt[qblk] - md;
    const float xtmax = xt[qblk + 63] - md;
    int lo = 0, hi = TY_;
    while (lo < hi) { int mid = (lo + hi) >> 1; if (yt[mid] + dist < xtmin) lo = mid + 1; else hi = mid; }
    const int klo = lo;
    lo = 0; hi = TY_;
    while (lo < hi) { int mid = (lo + hi) >> 1; if (yt[mid] <= xtmax) lo = mid + 1; else hi = mid; }
    const int khi = lo - 1;
    const int len = khi - klo + 1;

    int k0 = klo, k1 = klo;
    if (len > 0) {
        const int cnt = (len + NSPLIT - 1) / NSPLIT;
        k0 = klo + split * cnt;
        k1 = min(k0 + cnt, klo + len);
    }

    float xtq[4];
#pragma unroll
    for (int r = 0; r < 4; r++)
        xtq[r] = xt[qbase + quad * 4 + r] - md;

    const __bf16* qp = Qb + ((size_t)bh * TX_ + qbase + m16) * 64;
    const bf16x8 aq0 = *(const bf16x8*)(qp + quad * 8);
    const bf16x8 aq1 = *(const bf16x8*)(qp + 32 + quad * 8);

    float l[4];
    floatx4 o[4];
#pragma unroll
    for (int r = 0; r < 4; r++) l[r] = 0.f;
#pragma unroll
    for (int t = 0; t < 4; t++) o[t] = (floatx4){0.f, 0.f, 0.f, 0.f};

    for (int kc = k0; kc < k1; kc += 32) {
        const float yt0 = yt[min(kc + m16, TY_ - 1)];
        const float yt1 = yt[min(kc + 16 + m16, TY_ - 1)];

        __syncthreads();
        {
            const int krow = tid >> 3;
            const int kg = min(kc + krow, TY_ - 1);
            async_copy16(Kb + ((size_t)bh * TY_ + kg) * 64 + (tid & 7) * 8,
                         (char*)Kc + tid * 16);
            const int d = tid >> 2;
            const int kv = min(kc + (tid & 3) * 8, TY_ - 8);
            async_copy16(Vt + ((size_t)bh * 64 + d) * TY_ + kv,
                         (char*)Vc + tid * 16);
        }
        __syncthreads();

        const bf16x8 bk0h0 = *(const bf16x8*)(Kc + m16 * 64 + quad * 8);
        const bf16x8 bk1h0 = *(const bf16x8*)(Kc + m16 * 64 + 32 + quad * 8);
        const bf16x8 bk0h1 = *(const bf16x8*)(Kc + (16 + m16) * 64 + quad * 8);
        const bf16x8 bk1h1 = *(const bf16x8*)(Kc + (16 + m16) * 64 + 32 + quad * 8);
        floatx4 s0 = (floatx4){0.f, 0.f, 0.f, 0.f};
        floatx4 s1 = (floatx4){0.f, 0.f, 0.f, 0.f};
        s0 = __builtin_amdgcn_mfma_f32_16x16x32_bf16(aq0, bk0h0, s0, 0, 0, 0);
        s0 = __builtin_amdgcn_mfma_f32_16x16x32_bf16(aq1, bk1h0, s0, 0, 0, 0);
        s1 = __builtin_amdgcn_mfma_f32_16x16x32_bf16(aq0, bk0h1, s1, 0, 0, 0);
        s1 = __builtin_amdgcn_mfma_f32_16x16x32_bf16(aq1, bk1h1, s1, 0, 0, 0);

        const int kg0 = kc + m16;
        const int kg1 = kc + 16 + m16;
        __bf16* pt = Pt[wave];
#pragma unroll
        for (int r = 0; r < 4; r++) {
            const bool v0 = (kg0 < k1) && (xtq[r] >= yt0) && (xtq[r] <= yt0 + dist);
            const bool v1 = (kg1 < k1) && (xtq[r] >= yt1) && (xtq[r] <= yt1 + dist);
            const float p0 = v0 ? (float)(__bf16)__expf(s0[r]) : 0.f;
            const float p1 = v1 ? (float)(__bf16)__expf(s1[r]) : 0.f;
            l[r] += p0 + p1;
            pt[(quad * 4 + r) * 32 + m16]      = (__bf16)p0;
            pt[(quad * 4 + r) * 32 + 16 + m16] = (__bf16)p1;
        }
        const bf16x8 ap = *(const bf16x8*)(pt + m16 * 32 + quad * 8);
#pragma unroll
        for (int t = 0; t < 4; t++) {
            const bf16x8 bv = *(const bf16x8*)(Vc + (t * 16 + m16) * 32 + quad * 8);
            o[t] = __builtin_amdgcn_mfma_f32_16x16x32_bf16(ap, bv, o[t], 0, 0, 0);
        }
    }

#pragma unroll
    for (int r = 0; r < 4; r++) {
#pragma unroll
        for (int w = 1; w < 16; w <<= 1)
            l[r] += __shfl_xor(l[r], w);
    }

#pragma unroll
    for (int t = 0; t < 4; t++)
#pragma unroll
        for (int r = 0; r < 4; r++) {
            const size_t gr = (size_t)bh * TX_ + qbase + quad * 4 + r;
            pacc[((size_t)split * R_ + gr) * 64 + t * 16 + m16] = o[t][r];
        }
    if (m16 == 0) {
#pragma unroll
        for (int r = 0; r < 4; r++) {
            const size_t gr = (size_t)bh * TX_ + qbase + quad * 4 + r;
            pml[(size_t)split * R_ + gr] = l[r];
        }
    }
}

// ---------------------------------------------------------------------------
// Combine NSPLIT partials -> Ob bf16 (B,TX,C)
// ---------------------------------------------------------------------------
__global__ __launch_bounds__(256)
void combine_kernel(const float* __restrict__ pacc,
                    const float* __restrict__ pml,
                    __bf16* __restrict__ O)
{
    const int d   = threadIdx.x;
    const int sub = threadIdx.y;
    const size_t r = (size_t)blockIdx.x * 4 + sub;
    const int bh  = (int)(r / TX_);
    const int txg = (int)(r % TX_);
    const int b = bh / H_, h = bh % H_;

    float L = 0.f, val = 0.f;
#pragma unroll
    for (int s = 0; s < NSPLIT; s++) {
        L   += pml[(size_t)s * R_ + r];
        val += pacc[((size_t)s * R_ + r) * 64 + d];
    }
    const float o = (L > 0.f) ? val / L : 0.f;
    O[(size_t)(b * TX_ + txg) * C_ + h * D_ + d] = (__bf16)o;
}

// ---------------------------------------------------------------------------
// proj GEMM: out(M,768 f32) = A(M,768 bf16) @ Bt(768,768 bf16)^T
// 128x128 tile, BK=64 (two 32-k chunks per barrier pair).
// ---------------------------------------------------------------------------
__global__ __launch_bounds__(256)
void gemm_proj(const __bf16* __restrict__ A,
               const __bf16* __restrict__ Bt,
               float* __restrict__ out0)
{
    __shared__ __align__(16) float smem_f[8192];
    __bf16* smem_b = (__bf16*)smem_f;

    const int tid  = threadIdx.x;
    const int wave = tid >> 6;
    const int lane = tid & 63;
    const int m16  = lane & 15;
    const int quad = lane >> 4;
    const int wm   = wave >> 1;
    const int wn   = wave & 1;
    const int row0 = blockIdx.y * 128;
    const int n0   = blockIdx.x * 128;

    floatx4 acc[4][4];
#pragma unroll
    for (int i = 0; i < 4; i++)
#pragma unroll
        for (int j = 0; j < 4; j++) acc[i][j] = (floatx4){0.f, 0.f, 0.f, 0.f};

    int srow[4], scol[4];
#pragma unroll
    for (int j = 0; j < 4; j++) {
        int e = j * 2048 + wave * 512 + lane * 8;
        int e2 = e & 4095;
        srow[j] = e2 >> 5;
        scol[j] = e2 & 31;
    }

    for (int k0 = 0; k0 < C_; k0 += 64) {
        __syncthreads();
#pragma unroll
        for (int c = 0; c < 2; c++) {
            const int kk = k0 + c * 32;
#pragma unroll
            for (int j = 0; j < 4; j++) {
                const __bf16* src = (j < 2)
                    ? A  + (size_t)(row0 + srow[j]) * C_ + (kk + scol[j])
                    : Bt + (size_t)(n0   + srow[j]) * C_ + (kk + scol[j]);
                async_copy16(src, (char*)smem_f + c * 16384 + j * 4096 + wave * 1024);
            }
        }
        __syncthreads();

#pragma unroll
        for (int c = 0; c < 2; c++) {
            const __bf16* As = smem_b + c * 8192;
            const __bf16* Bs = As + 4096;
            bf16x8 af[4], bfr[4];
#pragma unroll
            for (int i = 0; i < 4; i++)
                af[i] = *(const bf16x8*)(As + (size_t)(wm * 64 + i * 16 + m16) * 32 + quad * 8);
#pragma unroll
            for (int j = 0; j < 4; j++)
                bfr[j] = *(const bf16x8*)(Bs + (size_t)(wn * 64 + j * 16 + m16) * 32 + quad * 8);
#pragma unroll
            for (int i = 0; i < 4; i++)
#pragma unroll
                for (int j = 0; j < 4; j++)
                    acc[i][j] = __builtin_amdgcn_mfma_f32_16x16x32_bf16(af[i], bfr[j], acc[i][j], 0, 0, 0);
        }
    }

    const int STR = 132;
    float* fs = smem_f;
#pragma unroll
    for (int i = 0; i < 4; i++) {
        __syncthreads();
#pragma unroll
        for (int j = 0; j < 4; j++) {
            const int col_l = wn * 64 + j * 16 + m16;
#pragma unroll
            for (int r = 0; r < 4; r++)
                fs[(wm * 16 + quad * 4 + r) * STR + col_l] = acc[i][j][r];
        }
        __syncthreads();
        const int r32 = tid >> 3;
        const int lc  = (tid & 7) * 4;
        const int row = row0 + (r32 >> 4) * 64 + i * 16 + (r32 & 15);
        float* gp = out0 + (size_t)row * C_ + n0;
#pragma unroll
        for (int c2 = 0; c2 < 4; c2++) {
            float4 v4 = *(const float4*)&fs[r32 * STR + c2 * 32 + lc];
            *(float4*)(gp + c2 * 32 + lc) = v4;
        }
    }
}

// ---------------------------------------------------------------------------
extern "C" void kernel_launch(void* const* d_in, const int* in_sizes, int n_in,
                              void* d_out, int out_size, void* d_ws, size_t ws_size,
                              hipStream_t stream)
{
    const float* x        = (const float*)d_in[0];
    const float* x_t      = (const float*)d_in[1];
    const float* y        = (const float*)d_in[2];
    const float* y_t      = (const float*)d_in[3];
    const int*   dist     = (const int*)d_in[4];
    const int*   min_dist = (const int*)d_in[5];
    const float* Wq       = (const float*)d_in[6];
    const float* Wkv      = (const float*)d_in[7];
    const float* Wproj    = (const float*)d_in[8];
    const float* inv_freq = (const float*)d_in[9];
    float* out = (float*)d_out;

    const size_t QN = (size_t)B_ * TX_ * C_;
    const size_t KN = (size_t)B_ * TY_ * C_;

    float* ws = (float*)d_ws;
    float* pacc = ws; ws += (size_t)NSPLIT * R_ * 64;
    float* pml  = ws; ws += (size_t)NSPLIT * R_;
    __bf16* bws = (__bf16*)ws;
    __bf16* xb    = bws; bws += QN;
    __bf16* yb    = bws; bws += KN;
    __bf16* Wqt   = bws; bws += (size_t)C_ * C_;
    __bf16* Wkvt  = bws; bws += (size_t)C_ * 2 * C_;
    __bf16* Wprt  = bws; bws += (size_t)C_ * C_;
    __bf16* Ob    = bws; bws += QN;
    __bf16* Qbh   = bws; bws += QN;          // [bh][TX][64]
    __bf16* Kbh   = bws; bws += KN;          // [bh][TY][64]
    __bf16* Vtb   = bws; bws += KN + 128;    // [bh][64][TY]

    prep<<<dim3(2304 + 3840), dim3(256), 0, stream>>>(
        x, xb, y, yb, Wq, Wqt, Wkv, Wkvt, Wproj, Wprt);

    gemm_qkv<<<dim3(1728), dim3(256), 0, stream>>>(
        xb, Wqt, yb, Wkvt, Qbh, Kbh, Vtb, x_t, y_t, inv_freq);

    attn_mfma<<<dim3(TX_ / 64, B_ * H_, NSPLIT), dim3(256), 0, stream>>>(
        Qbh, Kbh, Vtb, x_t, y_t, dist, min_dist, pacc, pml);

    combine_kernel<<<dim3((unsigned)(R_ / 4)), dim3(64, 4), 0, stream>>>(
        pacc, pml, Ob);

    gemm_proj<<<dim3(C_ / 128, (B_ * TX_) / 128), dim3(256), 0, stream>>>(
        Ob, Wprt, out);
}